// Round 5
// baseline (578.804 us; speedup 1.0000x reference)
//
#include <hip/hip_runtime.h>
#include <math.h>

// Problem constants
#define NA    50
#define NT    50
#define HIDK  128
#define NH    32
#define NC    16
#define NB    32
#define SAT   2500    // NA*NT
#define NS    2450    // (NA-1)*NT
#define NOUT  512     // NH*NC

// ============ K_fill: out[b][a][t][:] = bias (ego slice overwritten by k2) ============
__global__ __launch_bounds__(256) void k_fill(const float* __restrict__ bias,
                                              float* __restrict__ out) {
  size_t i = (size_t)blockIdx.x * 256 + threadIdx.x;
  float4 b4 = ((const float4*)bias)[i & 127];
  ((float4*)out)[i] = b4;
}

// ============ K0: PQ[j][k] = sum_c att[j][c] * W[(j%32)*16+c][k], j<32 src / j>=32 dst ===
__global__ __launch_bounds__(256) void k0_pq(const float* __restrict__ W,
                                             const float* __restrict__ att_src,
                                             const float* __restrict__ att_dst,
                                             float* __restrict__ PQ) {
  int g = blockIdx.x * 256 + threadIdx.x;   // 8192 total
  int j = g >> 7, k = g & 127;
  int hh = j & 31;
  const float* att = (j < 32) ? att_src : att_dst;
  float acc = 0.f;
  #pragma unroll
  for (int c = 0; c < 16; ++c)
    acc = fmaf(att[hh * 16 + c], W[(size_t)(hh * 16 + c) * 128 + k], acc);
  PQ[g] = acc;
}

// ============ K1: u[b][h][s] = x_row . p_h ; d[b][h][t] = x_ego_row . q_h ============
// GEMM (80000,128)@(128,64). 1.31 GFLOP (vs R4's 10.5: att vectors folded into W).
__global__ __launch_bounds__(256) void k1_ud(
    const float* __restrict__ X,     // (80000,128) = h input
    const float* __restrict__ PQ,    // (64,128)
    float* __restrict__ u,           // [b][h][2500]
    float* __restrict__ dv)          // [b][h][50]
{
  __shared__ float Ast[32][68];
  __shared__ float Bst[32][68];
  const int tid = threadIdx.x;
  const int m0 = blockIdx.x * 64;
  const int ty = tid >> 4, tx = tid & 15;
  float acc[4][4] = {};
  const int sr = tid >> 3, sc = tid & 7;

  for (int kc = 0; kc < 128; kc += 32) {
    #pragma unroll
    for (int L = 0; L < 2; ++L) {
      int row = sr + L * 32;
      float4 v = *(const float4*)&X[(size_t)(m0 + row) * 128 + kc + sc * 4];
      Ast[sc*4+0][row] = v.x; Ast[sc*4+1][row] = v.y;
      Ast[sc*4+2][row] = v.z; Ast[sc*4+3][row] = v.w;
      float4 w = *(const float4*)&PQ[(size_t)row * 128 + kc + sc * 4];
      Bst[sc*4+0][row] = w.x; Bst[sc*4+1][row] = w.y;
      Bst[sc*4+2][row] = w.z; Bst[sc*4+3][row] = w.w;
    }
    __syncthreads();
    #pragma unroll
    for (int k = 0; k < 32; ++k) {
      float4 a4 = *(const float4*)&Ast[k][ty * 4];
      float4 b4 = *(const float4*)&Bst[k][tx * 4];
      float a[4] = {a4.x, a4.y, a4.z, a4.w};
      float bb[4] = {b4.x, b4.y, b4.z, b4.w};
      #pragma unroll
      for (int i = 0; i < 4; ++i)
        #pragma unroll
        for (int j = 0; j < 4; ++j)
          acc[i][j] = fmaf(a[i], bb[j], acc[i][j]);
    }
    __syncthreads();
  }

  #pragma unroll
  for (int i = 0; i < 4; ++i) {
    int m = m0 + ty * 4 + i;
    int b = m / SAT, s = m - b * SAT;
    #pragma unroll
    for (int jj = 0; jj < 4; ++jj) {
      int col = tx * 4 + jj;
      if (col < 32)
        u[(size_t)(b * 32 + col) * SAT + s] = acc[i][jj];
      else if (s < NT)
        dv[(size_t)(b * 32 + col - 32) * NT + s] = acc[i][jj];
    }
  }
}

// ============ K2: bucket-decomposed attention, aggregated in x-space ============
// w(s,t) = pos ? e1_s*F1_t : e2_s*F2_t with pos <=> u_s >= theta_t = -d_t.
// Counting-sort s by bucket beta(s)=#{theta<=u_s} (LDS atomics only for the
// one-off histogram/scatter — R2 lesson: NO atomics on the per-element path).
// Then per-channel threads stream x in sorted order with REGISTER accumulators,
// flushing once per segment -> B[bucket][channel]; suffix/prefix scans; project
// through W_h at the very end (Y@W^T), so aggregation runs in 128-dim x-space
// and the 512-dim xw tensor is never materialized.
__global__ __launch_bounds__(256) void k2_attn(
    const float* __restrict__ X,     // (32,2500,128)
    const float* __restrict__ u,     // [b][h][2500]
    const float* __restrict__ dv,    // [b][h][50]
    const float* __restrict__ W,     // (512,128)
    const float* __restrict__ bias,  // (512)
    float* __restrict__ out)
{
  const int b = blockIdx.x;          // blockIdx.x = b => linear id = h*32+b
  const int h = blockIdx.y;          //  => all 32 h-blocks of b on XCD b%8 (L2 reuse)
  const int tid = threadIdx.x;

  __shared__ float B1[51][130];      // [bucket][channel]; col 128 = weight-sum (z)
  __shared__ float B2[51][130];
  __shared__ float2 sE[NS];          // sorted (e1,e2)
  __shared__ unsigned short sIdx[NS];// sorted original s
  __shared__ float sTheta[50], sD[50], sF1[50], sF2[50];
  __shared__ int   sRank[50];
  __shared__ unsigned int off[52];
  __shared__ unsigned int offCur[51];
  __shared__ float red[4];
  __shared__ float sMaxU;

  float* sU = &B1[0][0];             // alias: raw u; dead before F overwrites B1

  const size_t bh = (size_t)b * 32 + h;
  const float* uP = u + bh * SAT + NT;   // skip ego rows
  for (int i = tid; i < NS; i += 256) sU[i] = uP[i];
  if (tid < 50) sD[tid] = dv[bh * NT + tid];
  if (tid < 51) offCur[tid] = 0;     // histogram
  __syncthreads();

  // maxU
  float mx = -1e30f;
  for (int i = tid; i < NS; i += 256) mx = fmaxf(mx, sU[i]);
  #pragma unroll
  for (int o = 32; o; o >>= 1) mx = fmaxf(mx, __shfl_xor(mx, o));
  if ((tid & 63) == 0) red[tid >> 6] = mx;
  __syncthreads();
  if (tid == 0) sMaxU = fmaxf(fmaxf(red[0], red[1]), fmaxf(red[2], red[3]));
  __syncthreads();
  const float maxU = sMaxU;

  // theta rank-sort + per-query factors (exact compare in u-domain)
  if (tid < 50) {
    float th = -sD[tid];
    int r = 0;
    for (int t2 = 0; t2 < 50; ++t2) {
      float th2 = -sD[t2];
      r += (th2 < th) || (th2 == th && t2 < tid);
    }
    sRank[tid] = r;
    sTheta[r] = th;
    float x = maxU + sD[tid];
    float L = (x >= 0.f) ? x : 0.2f * x;
    sF1[tid] = __expf(x - L);
    sF2[tid] = __expf(0.2f * x - L);
  }
  __syncthreads();

  // histogram of buckets
  for (int i = tid; i < NS; i += 256) {
    float uu = sU[i];
    int lo = 0, hi = 50;
    while (lo < hi) { int mid = (lo + hi) >> 1; if (sTheta[mid] <= uu) lo = mid + 1; else hi = mid; }
    atomicAdd(&offCur[lo], 1u);
  }
  __syncthreads();
  if (tid == 0) {
    unsigned run = 0;
    for (int k = 0; k < 51; ++k) { unsigned c = offCur[k]; off[k] = run; run += c; }
    off[51] = run;  // 2450
  }
  __syncthreads();
  if (tid < 51) offCur[tid] = off[tid];
  __syncthreads();

  // scatter: sorted (e1,e2,s)
  for (int i = tid; i < NS; i += 256) {
    float uu = sU[i];
    int lo = 0, hi = 50;
    while (lo < hi) { int mid = (lo + hi) >> 1; if (sTheta[mid] <= uu) lo = mid + 1; else hi = mid; }
    unsigned pos = atomicAdd(&offCur[lo], 1u);
    sE[pos] = make_float2(__expf(uu - maxU), __expf(0.2f * (uu - maxU)));
    sIdx[pos] = (unsigned short)(i + NT);
  }
  __syncthreads();

  // F: segment accumulation, register accumulators, flush per bucket.
  // 256 threads = 2 halves x 128 channels; halves own disjoint segment ranges.
  {
    const int half = tid >> 7;
    const int c = tid & 127;
    const int segLo = half ? 26 : 0;
    const int segHi = half ? 51 : 26;
    const float* xc = X + (size_t)b * SAT * 128 + c;
    int i = off[segLo];
    for (int seg = segLo; seg < segHi; ++seg) {
      const int i1 = off[seg + 1];
      float a1 = 0.f, a2 = 0.f;
      #pragma unroll 4
      for (; i < i1; ++i) {
        float2 e = sE[i];
        int s = sIdx[i];
        float xv = xc[s * 128];
        a1 = fmaf(e.x, xv, a1);
        a2 = fmaf(e.y, xv, a2);
      }
      B1[seg][c] = a1;
      B2[seg][c] = a2;
    }
  }
  __syncthreads();

  // z-channel (col 128): per-bucket sums of e1 / e2
  if (tid < 102) {
    int k = tid % 51, which = tid / 51;
    unsigned i0 = off[k], i1 = off[k + 1];
    float a = 0.f;
    for (unsigned i = i0; i < i1; ++i)
      a += which ? sE[i].y : sE[i].x;
    if (which) B2[k][128] = a; else B1[k][128] = a;
  }
  __syncthreads();

  // scans over 51 buckets: B1 -> exclusive suffix, B2 -> inclusive prefix (129 channels)
  for (int task = tid; task < 258; task += 256) {
    int which = task >= 129;
    int c = task - which * 129;
    if (which == 0) {
      float run = 0.f;
      for (int k = 50; k >= 0; --k) { float tmp = B1[k][c]; B1[k][c] = run; run += tmp; }
    } else {
      float run = 0.f;
      for (int k = 0; k <= 50; ++k) { run += B2[k][c]; B2[k][c] = run; }
    }
  }
  __syncthreads();

  // stage W_h transposed (aliases sE — dead after z-pass)
  float* WshT = (float*)sE;           // [128][16]
  const float* Wh = W + (size_t)h * 16 * 128;
  for (int v = tid; v < 2048; v += 256) {
    int k = v >> 4, cout = v & 15;
    WshT[k * 16 + cout] = Wh[(size_t)cout * 128 + k];
  }
  __syncthreads();

  // epilogue: out[t][cout] = (F1*S1 + F2*S2).Wh / z + bias  (800 tasks, grid-stride:
  // R3 lesson — never `if (tid < 800)` with 256 threads)
  for (int task = tid; task < NT * NC; task += 256) {
    int t = task >> 4, cout = task & 15;
    int r = sRank[t];
    float F1 = sF1[t], F2 = sF2[t];
    float z = F1 * B1[r][128] + F2 * B2[r][128];
    const float* b1r = &B1[r][0];
    const float* b2r = &B2[r][0];
    float n1 = 0.f, n2 = 0.f;
    #pragma unroll 4
    for (int c = 0; c < 128; ++c) {
      float w = WshT[c * 16 + cout];
      n1 = fmaf(b1r[c], w, n1);
      n2 = fmaf(b2r[c], w, n2);
    }
    out[((size_t)b * SAT + t) * NOUT + h * 16 + cout] =
        (F1 * n1 + F2 * n2) / z + bias[h * 16 + cout];
  }
}

extern "C" void kernel_launch(void* const* d_in, const int* in_sizes, int n_in,
                              void* d_out, int out_size, void* d_ws, size_t ws_size,
                              hipStream_t stream) {
  const float* X       = (const float*)d_in[0];  // h (32,50,50,128)
  const float* Wm      = (const float*)d_in[1];  // W (512,128)
  const float* att_src = (const float*)d_in[2];  // (32,16)
  const float* att_dst = (const float*)d_in[3];  // (32,16)
  const float* bias    = (const float*)d_in[4];  // (512,)
  float* out = (float*)d_out;

  // workspace: PQ 8192 f | u 2.56M f | dv 51200 f  (~10.5 MB of d_ws)
  float* PQ = (float*)d_ws;
  float* u  = PQ + 64 * 128;
  float* dv = u + (size_t)NB * NH * SAT;

  hipLaunchKernelGGL(k_fill, dim3(40000), dim3(256), 0, stream, bias, out);
  hipLaunchKernelGGL(k0_pq, dim3(32), dim3(256), 0, stream, Wm, att_src, att_dst, PQ);
  hipLaunchKernelGGL(k1_ud, dim3(1250), dim3(256), 0, stream, X, PQ, u, dv);
  hipLaunchKernelGGL(k2_attn, dim3(NB, NH), dim3(256), 0, stream,
                     X, u, dv, Wm, bias, out);
}

// Round 6
// 446.401 us; speedup vs baseline: 1.2966x; 1.2966x over previous
//
#include <hip/hip_runtime.h>
#include <math.h>

// Problem constants
#define NA    50
#define NT    50
#define HIDK  128
#define NH    32
#define NC    16
#define NB    32
#define SAT   2500    // NA*NT
#define NS    2450    // (NA-1)*NT
#define NOUT  512     // NH*NC

// ============ K_fill: out[b][a][t][:] = bias (ego slice overwritten by k2) ============
__global__ __launch_bounds__(256) void k_fill(const float* __restrict__ bias,
                                              float* __restrict__ out) {
  size_t i = (size_t)blockIdx.x * 256 + threadIdx.x;
  float4 b4 = ((const float4*)bias)[i & 127];
  ((float4*)out)[i] = b4;
}

// ============ K0: PQ[j][k] = sum_c att[j][c] * W[(j%32)*16+c][k] ============
__global__ __launch_bounds__(256) void k0_pq(const float* __restrict__ W,
                                             const float* __restrict__ att_src,
                                             const float* __restrict__ att_dst,
                                             float* __restrict__ PQ) {
  int g = blockIdx.x * 256 + threadIdx.x;   // 8192 total
  int j = g >> 7, k = g & 127;
  int hh = j & 31;
  const float* att = (j < 32) ? att_src : att_dst;
  float acc = 0.f;
  #pragma unroll
  for (int c = 0; c < 16; ++c)
    acc = fmaf(att[hh * 16 + c], W[(size_t)(hh * 16 + c) * 128 + k], acc);
  PQ[g] = acc;
}

// ============ K1: u[b][h][s] = x_row . p_h ; d[b][h][t] = x_ego_row . q_h ============
__global__ __launch_bounds__(256) void k1_ud(
    const float* __restrict__ X,     // (80000,128)
    const float* __restrict__ PQ,    // (64,128)
    float* __restrict__ u,           // [b][h][2500]
    float* __restrict__ dv)          // [b][h][50]
{
  __shared__ float Ast[32][68];
  __shared__ float Bst[32][68];
  const int tid = threadIdx.x;
  const int m0 = blockIdx.x * 64;
  const int ty = tid >> 4, tx = tid & 15;
  float acc[4][4] = {};
  const int sr = tid >> 3, sc = tid & 7;

  for (int kc = 0; kc < 128; kc += 32) {
    #pragma unroll
    for (int L = 0; L < 2; ++L) {
      int row = sr + L * 32;
      float4 v = *(const float4*)&X[(size_t)(m0 + row) * 128 + kc + sc * 4];
      Ast[sc*4+0][row] = v.x; Ast[sc*4+1][row] = v.y;
      Ast[sc*4+2][row] = v.z; Ast[sc*4+3][row] = v.w;
      float4 w = *(const float4*)&PQ[(size_t)row * 128 + kc + sc * 4];
      Bst[sc*4+0][row] = w.x; Bst[sc*4+1][row] = w.y;
      Bst[sc*4+2][row] = w.z; Bst[sc*4+3][row] = w.w;
    }
    __syncthreads();
    #pragma unroll
    for (int k = 0; k < 32; ++k) {
      float4 a4 = *(const float4*)&Ast[k][ty * 4];
      float4 b4 = *(const float4*)&Bst[k][tx * 4];
      float a[4] = {a4.x, a4.y, a4.z, a4.w};
      float bb[4] = {b4.x, b4.y, b4.z, b4.w};
      #pragma unroll
      for (int i = 0; i < 4; ++i)
        #pragma unroll
        for (int j = 0; j < 4; ++j)
          acc[i][j] = fmaf(a[i], bb[j], acc[i][j]);
    }
    __syncthreads();
  }

  #pragma unroll
  for (int i = 0; i < 4; ++i) {
    int m = m0 + ty * 4 + i;
    int b = m / SAT, s = m - b * SAT;
    #pragma unroll
    for (int jj = 0; jj < 4; ++jj) {
      int col = tx * 4 + jj;
      if (col < 32)
        u[(size_t)(b * 32 + col) * SAT + s] = acc[i][jj];
      else if (s < NT)
        dv[(size_t)(b * 32 + col - 32) * NT + s] = acc[i][jj];
    }
  }
}

// ============ K2: bucket-decomposed attention in x-space, latency-tolerant F ============
// (R5 lesson: per-thread serial indirected scalar loads = ~750 cyc/source. Fix:
//  wave-contiguous sorted ranges, full-row coalesced float4 loads, flush-on-
//  boundary with rare LDS atomics, 512 threads / 78.6KB LDS -> 2 blocks/CU.)
__global__ __launch_bounds__(512) void k2_attn(
    const float* __restrict__ X,     // (32,2500,128)
    const float* __restrict__ u,     // [b][h][2500]
    const float* __restrict__ dv,    // [b][h][50]
    const float* __restrict__ W,     // (512,128)
    const float* __restrict__ bias,  // (512)
    float* __restrict__ out)
{
  const int id = blockIdx.x;
  const int b  = (id & 7) + 8 * (id >> 8);   // <=2 X-slices per XCD L2 window
  const int h  = (id >> 3) & 31;
  const int tid = threadIdx.x;

  __shared__ float Bb[2][51][129];   // [which][bucket][c]; c==128 = z   52.6 KB
  __shared__ float2 sE[NS];          // sorted (e1,e2)                   19.6 KB
  __shared__ unsigned short sIdx[NS];// sorted sat-index                  4.9 KB
  __shared__ float sTheta[50], sD[50], sF1[50], sF2[50];
  __shared__ int   sRank[50];
  __shared__ int   offs[52];
  __shared__ int   offCur[51];
  __shared__ float red[8];
  __shared__ float sMaxU;

  float* sU = &Bb[0][0][0];                       // alias (dead before F)
  unsigned short* sBeta = (unsigned short*)&Bb[1][0][0];  // alias (dead before F)

  const size_t bh = (size_t)b * 32 + h;
  const float* uP = u + bh * SAT + NT;   // skip ego rows
  for (int i = tid; i < NS; i += 512) sU[i] = uP[i];
  if (tid < 50) sD[tid] = dv[bh * NT + tid];
  if (tid < 51) offCur[tid] = 0;
  __syncthreads();

  // ---- maxU ----
  float mx = -1e30f;
  for (int i = tid; i < NS; i += 512) mx = fmaxf(mx, sU[i]);
  #pragma unroll
  for (int o = 32; o; o >>= 1) mx = fmaxf(mx, __shfl_xor(mx, o));
  if ((tid & 63) == 0) red[tid >> 6] = mx;
  __syncthreads();
  if (tid == 0) {
    float m2 = red[0];
    #pragma unroll
    for (int k = 1; k < 8; ++k) m2 = fmaxf(m2, red[k]);
    sMaxU = m2;
  }
  __syncthreads();
  const float maxU = sMaxU;

  // ---- theta rank-sort + per-query factors ----
  if (tid < 50) {
    float th = -sD[tid];
    int r = 0;
    for (int t2 = 0; t2 < 50; ++t2) {
      float th2 = -sD[t2];
      r += (th2 < th) || (th2 == th && t2 < tid);
    }
    sRank[tid] = r;
    sTheta[r] = th;
    float x = maxU + sD[tid];
    float L = (x >= 0.f) ? x : 0.2f * x;
    sF1[tid] = __expf(x - L);
    sF2[tid] = __expf(0.2f * x - L);
  }
  __syncthreads();

  // ---- histogram (store beta once; reuse in scatter) ----
  for (int i = tid; i < NS; i += 512) {
    float uu = sU[i];
    int lo = 0, hi = 50;
    while (lo < hi) { int mid = (lo + hi) >> 1; if (sTheta[mid] <= uu) lo = mid + 1; else hi = mid; }
    sBeta[i] = (unsigned short)lo;
    atomicAdd(&offCur[lo], 1);
  }
  __syncthreads();
  if (tid == 0) {
    int run = 0;
    for (int k = 0; k < 51; ++k) { int c = offCur[k]; offs[k] = run; run += c; }
    offs[51] = run;  // 2450
  }
  __syncthreads();
  if (tid < 51) offCur[tid] = offs[tid];
  __syncthreads();

  // ---- scatter: sorted (e1,e2,satIdx) ----
  for (int i = tid; i < NS; i += 512) {
    float uu = sU[i];
    int beta = sBeta[i];
    int pos = atomicAdd(&offCur[beta], 1);
    sE[pos] = make_float2(__expf(uu - maxU), __expf(0.2f * (uu - maxU)));
    sIdx[pos] = (unsigned short)(i + NT);
  }
  __syncthreads();

  // ---- zero bucket sums (sU/sBeta aliases now dead) ----
  for (int i = tid; i < 2 * 51 * 129; i += 512) (&Bb[0][0][0])[i] = 0.f;
  __syncthreads();

  // ---- F: wave-contiguous sorted ranges, coalesced row loads ----
  {
    const int wave = tid >> 6;        // 0..7
    const int lane = tid & 63;
    const int slot = lane >> 5;       // 0/1: which source of the pair
    const int cq   = lane & 31;       // channel quad cq*4..+3
    const int wStart = (NS * wave) >> 3;
    const int wEnd   = (NS * (wave + 1)) >> 3;
    const float* xb = X + (size_t)b * SAT * HIDK + cq * 4;
    float a1x=0.f,a1y=0.f,a1z=0.f,a1w=0.f;
    float a2x=0.f,a2y=0.f,a2z=0.f,a2w=0.f;
    float z1 = 0.f, z2 = 0.f;
    int segIdx = 0;
    int nextOff = offs[1];
    bool dirty = false;
    for (int i = wStart + slot; i < wEnd; i += 2) {
      while (i >= nextOff) {
        if (dirty) {
          atomicAdd(&Bb[0][segIdx][cq*4+0], a1x);
          atomicAdd(&Bb[0][segIdx][cq*4+1], a1y);
          atomicAdd(&Bb[0][segIdx][cq*4+2], a1z);
          atomicAdd(&Bb[0][segIdx][cq*4+3], a1w);
          atomicAdd(&Bb[1][segIdx][cq*4+0], a2x);
          atomicAdd(&Bb[1][segIdx][cq*4+1], a2y);
          atomicAdd(&Bb[1][segIdx][cq*4+2], a2z);
          atomicAdd(&Bb[1][segIdx][cq*4+3], a2w);
          if (cq == 0) {
            atomicAdd(&Bb[0][segIdx][128], z1);
            atomicAdd(&Bb[1][segIdx][128], z2);
            z1 = 0.f; z2 = 0.f;
          }
          a1x=a1y=a1z=a1w=0.f; a2x=a2y=a2z=a2w=0.f;
          dirty = false;
        }
        ++segIdx;
        nextOff = offs[segIdx + 1];
      }
      float2 e = sE[i];
      int s = sIdx[i];
      float4 xv = *(const float4*)(xb + (size_t)s * HIDK);
      a1x = fmaf(e.x, xv.x, a1x); a1y = fmaf(e.x, xv.y, a1y);
      a1z = fmaf(e.x, xv.z, a1z); a1w = fmaf(e.x, xv.w, a1w);
      a2x = fmaf(e.y, xv.x, a2x); a2y = fmaf(e.y, xv.y, a2y);
      a2z = fmaf(e.y, xv.z, a2z); a2w = fmaf(e.y, xv.w, a2w);
      if (cq == 0) { z1 += e.x; z2 += e.y; }
      dirty = true;
    }
    if (dirty) {
      atomicAdd(&Bb[0][segIdx][cq*4+0], a1x);
      atomicAdd(&Bb[0][segIdx][cq*4+1], a1y);
      atomicAdd(&Bb[0][segIdx][cq*4+2], a1z);
      atomicAdd(&Bb[0][segIdx][cq*4+3], a1w);
      atomicAdd(&Bb[1][segIdx][cq*4+0], a2x);
      atomicAdd(&Bb[1][segIdx][cq*4+1], a2y);
      atomicAdd(&Bb[1][segIdx][cq*4+2], a2z);
      atomicAdd(&Bb[1][segIdx][cq*4+3], a2w);
      if (cq == 0) {
        atomicAdd(&Bb[0][segIdx][128], z1);
        atomicAdd(&Bb[1][segIdx][128], z2);
      }
    }
  }
  __syncthreads();

  // ---- stage W_h^T (aliases sE — dead after F) + scans ----
  float* WshT = (float*)sE;           // [128][16]
  const float* Wh = W + (size_t)h * 16 * 128;
  for (int v = tid; v < 2048; v += 512) {
    int k = v >> 4, cout = v & 15;
    WshT[k * 16 + cout] = Wh[(size_t)cout * 128 + k];
  }
  // scans over 51 buckets: which=0 -> exclusive suffix, which=1 -> inclusive prefix
  for (int task = tid; task < 258; task += 512) {
    int which = task >= 129;
    int c = task - which * 129;
    if (which == 0) {
      float run = 0.f;
      for (int k = 50; k >= 0; --k) { float tmp = Bb[0][k][c]; Bb[0][k][c] = run; run += tmp; }
    } else {
      float run = 0.f;
      for (int k = 0; k <= 50; ++k) { run += Bb[1][k][c]; Bb[1][k][c] = run; }
    }
  }
  __syncthreads();

  // ---- epilogue: project through W_h, divide, bias, store ego slice ----
  for (int task = tid; task < NT * NC; task += 512) {
    int t = task >> 4, cout = task & 15;
    int r = sRank[t];
    float F1 = sF1[t], F2 = sF2[t];
    float z = F1 * Bb[0][r][128] + F2 * Bb[1][r][128];
    const float* b1r = &Bb[0][r][0];
    const float* b2r = &Bb[1][r][0];
    float n1 = 0.f, n2 = 0.f;
    #pragma unroll 4
    for (int c = 0; c < 128; ++c) {
      float w = WshT[c * 16 + cout];
      n1 = fmaf(b1r[c], w, n1);
      n2 = fmaf(b2r[c], w, n2);
    }
    out[((size_t)b * SAT + t) * NOUT + h * 16 + cout] =
        (F1 * n1 + F2 * n2) / z + bias[h * 16 + cout];
  }
}

extern "C" void kernel_launch(void* const* d_in, const int* in_sizes, int n_in,
                              void* d_out, int out_size, void* d_ws, size_t ws_size,
                              hipStream_t stream) {
  const float* X       = (const float*)d_in[0];  // h (32,50,50,128)
  const float* Wm      = (const float*)d_in[1];  // W (512,128)
  const float* att_src = (const float*)d_in[2];  // (32,16)
  const float* att_dst = (const float*)d_in[3];  // (32,16)
  const float* bias    = (const float*)d_in[4];  // (512,)
  float* out = (float*)d_out;

  float* PQ = (float*)d_ws;
  float* u  = PQ + 64 * 128;
  float* dv = u + (size_t)NB * NH * SAT;

  hipLaunchKernelGGL(k_fill, dim3(40000), dim3(256), 0, stream, bias, out);
  hipLaunchKernelGGL(k0_pq, dim3(32), dim3(256), 0, stream, Wm, att_src, att_dst, PQ);
  hipLaunchKernelGGL(k1_ud, dim3(1250), dim3(256), 0, stream, X, PQ, u, dv);
  hipLaunchKernelGGL(k2_attn, dim3(1024), dim3(512), 0, stream,
                     X, u, dv, Wm, bias, out);
}

// Round 7
// 323.808 us; speedup vs baseline: 1.7875x; 1.3786x over previous
//
#include <hip/hip_runtime.h>
#include <math.h>

// Problem constants
#define NA    50
#define NT    50
#define HIDK  128
#define NH    32
#define NC    16
#define NB    32
#define SAT   2500    // NA*NT
#define NS    2450    // (NA-1)*NT
#define NOUT  512     // NH*NC

// ============ K_fill: out[b][a][t][:] = bias (ego slice overwritten by k2) ============
__global__ __launch_bounds__(256) void k_fill(const float* __restrict__ bias,
                                              float* __restrict__ out) {
  size_t i = (size_t)blockIdx.x * 256 + threadIdx.x;
  float4 b4 = ((const float4*)bias)[i & 127];
  ((float4*)out)[i] = b4;
}

// ============ K0: PQ[j][k] = sum_c att[j][c] * W[(j%32)*16+c][k] ============
__global__ __launch_bounds__(256) void k0_pq(const float* __restrict__ W,
                                             const float* __restrict__ att_src,
                                             const float* __restrict__ att_dst,
                                             float* __restrict__ PQ) {
  int g = blockIdx.x * 256 + threadIdx.x;   // 8192 total
  int j = g >> 7, k = g & 127;
  int hh = j & 31;
  const float* att = (j < 32) ? att_src : att_dst;
  float acc = 0.f;
  #pragma unroll
  for (int c = 0; c < 16; ++c)
    acc = fmaf(att[hh * 16 + c], W[(size_t)(hh * 16 + c) * 128 + k], acc);
  PQ[g] = acc;
}

// ============ K1: u[b][h][s] = x_row . p_h ; d[b][h][t] = x_ego_row . q_h ============
__global__ __launch_bounds__(256) void k1_ud(
    const float* __restrict__ X,     // (80000,128)
    const float* __restrict__ PQ,    // (64,128)
    float* __restrict__ u,           // [b][h][2500]
    float* __restrict__ dv)          // [b][h][50]
{
  __shared__ float Ast[32][68];
  __shared__ float Bst[32][68];
  const int tid = threadIdx.x;
  const int m0 = blockIdx.x * 64;
  const int ty = tid >> 4, tx = tid & 15;
  float acc[4][4] = {};
  const int sr = tid >> 3, sc = tid & 7;

  for (int kc = 0; kc < 128; kc += 32) {
    #pragma unroll
    for (int L = 0; L < 2; ++L) {
      int row = sr + L * 32;
      float4 v = *(const float4*)&X[(size_t)(m0 + row) * 128 + kc + sc * 4];
      Ast[sc*4+0][row] = v.x; Ast[sc*4+1][row] = v.y;
      Ast[sc*4+2][row] = v.z; Ast[sc*4+3][row] = v.w;
      float4 w = *(const float4*)&PQ[(size_t)row * 128 + kc + sc * 4];
      Bst[sc*4+0][row] = w.x; Bst[sc*4+1][row] = w.y;
      Bst[sc*4+2][row] = w.z; Bst[sc*4+3][row] = w.w;
    }
    __syncthreads();
    #pragma unroll
    for (int k = 0; k < 32; ++k) {
      float4 a4 = *(const float4*)&Ast[k][ty * 4];
      float4 b4 = *(const float4*)&Bst[k][tx * 4];
      float a[4] = {a4.x, a4.y, a4.z, a4.w};
      float bb[4] = {b4.x, b4.y, b4.z, b4.w};
      #pragma unroll
      for (int i = 0; i < 4; ++i)
        #pragma unroll
        for (int j = 0; j < 4; ++j)
          acc[i][j] = fmaf(a[i], bb[j], acc[i][j]);
    }
    __syncthreads();
  }

  #pragma unroll
  for (int i = 0; i < 4; ++i) {
    int m = m0 + ty * 4 + i;
    int b = m / SAT, s = m - b * SAT;
    #pragma unroll
    for (int jj = 0; jj < 4; ++jj) {
      int col = tx * 4 + jj;
      if (col < 32)
        u[(size_t)(b * 32 + col) * SAT + s] = acc[i][jj];
      else if (s < NT)
        dv[(size_t)(b * 32 + col - 32) * NT + s] = acc[i][jj];
    }
  }
}

// ============ K2: bucket-decomposed attention in x-space ============
// R5 lesson: serial indirect scalar loads -> 750 cyc/src. R6 lesson: boundary
// control flow inside the hot loop kills unrolling -> full LDS+L2 latency per
// iteration (4000 cyc/iter, VALUBusy 22%). Fix: segments are known before the
// loop, so waves own whole segments (wave w: segs w, w+8, ...) -> branch-free
// inner loop, manual unroll x4 with 4 loads in flight, exclusive non-atomic
// flush (cross-slot shfl), no bucket zero-init needed.
__global__ __launch_bounds__(512) void k2_attn(
    const float* __restrict__ X,     // (32,2500,128)
    const float* __restrict__ u,     // [b][h][2500]
    const float* __restrict__ dv,    // [b][h][50]
    const float* __restrict__ W,     // (512,128)
    const float* __restrict__ bias,  // (512)
    float* __restrict__ out)
{
  const int id = blockIdx.x;
  const int b  = (id & 7) + 8 * (id >> 8);   // <=2 X-slices per XCD L2 window
  const int h  = (id >> 3) & 31;
  const int tid = threadIdx.x;

  __shared__ float Bb[2][51][129];   // [which][bucket][c]; c==128 = z   52.6 KB
  __shared__ float2 sE[NS];          // sorted (e1,e2)                   19.6 KB
  __shared__ unsigned short sIdx[NS];// sorted sat-index                  4.9 KB
  __shared__ float sTheta[50], sD[50], sF1[50], sF2[50];
  __shared__ int   sRank[50];
  __shared__ int   offs[52];
  __shared__ int   offCur[51];
  __shared__ float red[8];
  __shared__ float sMaxU;

  float* sU = &Bb[0][0][0];                       // alias (dead before F)
  unsigned short* sBeta = (unsigned short*)&Bb[1][0][0];  // alias (dead before F)

  const size_t bh = (size_t)b * 32 + h;
  const float* uP = u + bh * SAT + NT;   // skip ego rows
  for (int i = tid; i < NS; i += 512) sU[i] = uP[i];
  if (tid < 50) sD[tid] = dv[bh * NT + tid];
  if (tid < 51) offCur[tid] = 0;
  __syncthreads();

  // ---- maxU ----
  float mx = -1e30f;
  for (int i = tid; i < NS; i += 512) mx = fmaxf(mx, sU[i]);
  #pragma unroll
  for (int o = 32; o; o >>= 1) mx = fmaxf(mx, __shfl_xor(mx, o));
  if ((tid & 63) == 0) red[tid >> 6] = mx;
  __syncthreads();
  if (tid == 0) {
    float m2 = red[0];
    #pragma unroll
    for (int k = 1; k < 8; ++k) m2 = fmaxf(m2, red[k]);
    sMaxU = m2;
  }
  __syncthreads();
  const float maxU = sMaxU;

  // ---- theta rank-sort + per-query factors ----
  if (tid < 50) {
    float th = -sD[tid];
    int r = 0;
    for (int t2 = 0; t2 < 50; ++t2) {
      float th2 = -sD[t2];
      r += (th2 < th) || (th2 == th && t2 < tid);
    }
    sRank[tid] = r;
    sTheta[r] = th;
    float x = maxU + sD[tid];
    float L = (x >= 0.f) ? x : 0.2f * x;
    sF1[tid] = __expf(x - L);
    sF2[tid] = __expf(0.2f * x - L);
  }
  __syncthreads();

  // ---- histogram (store beta once; reuse in scatter) ----
  for (int i = tid; i < NS; i += 512) {
    float uu = sU[i];
    int lo = 0, hi = 50;
    while (lo < hi) { int mid = (lo + hi) >> 1; if (sTheta[mid] <= uu) lo = mid + 1; else hi = mid; }
    sBeta[i] = (unsigned short)lo;
    atomicAdd(&offCur[lo], 1);
  }
  __syncthreads();
  if (tid == 0) {
    int run = 0;
    for (int k = 0; k < 51; ++k) { int c = offCur[k]; offs[k] = run; run += c; }
    offs[51] = run;  // 2450
  }
  __syncthreads();
  if (tid < 51) offCur[tid] = offs[tid];
  __syncthreads();

  // ---- scatter: sorted (e1,e2,satIdx) ----
  for (int i = tid; i < NS; i += 512) {
    float uu = sU[i];
    int beta = sBeta[i];
    int pos = atomicAdd(&offCur[beta], 1);
    sE[pos] = make_float2(__expf(uu - maxU), __expf(0.2f * (uu - maxU)));
    sIdx[pos] = (unsigned short)(i + NT);
  }
  __syncthreads();

  // ---- F: wave-owned segments, branch-free unrolled inner loop ----
  {
    const int wave = tid >> 6;        // 0..7
    const int lane = tid & 63;
    const int slot = lane >> 5;       // which source of the pair
    const int cq   = lane & 31;       // channel quad cq*4..+3
    const float* xb = X + (size_t)b * SAT * HIDK + cq * 4;

    for (int seg = wave; seg < 51; seg += 8) {
      const int i0 = offs[seg], i1 = offs[seg + 1];
      float a1[4] = {0.f, 0.f, 0.f, 0.f};
      float a2[4] = {0.f, 0.f, 0.f, 0.f};
      float z1 = 0.f, z2 = 0.f;
      int i = i0 + slot;
      // unroll x4: 4 independent LDS pair-reads, 4 loads in flight, then FMAs
      for (; i + 6 < i1; i += 8) {
        float2 e0 = sE[i];     float2 e1 = sE[i + 2];
        float2 e2 = sE[i + 4]; float2 e3 = sE[i + 6];
        int s0 = sIdx[i];     int s1 = sIdx[i + 2];
        int s2 = sIdx[i + 4]; int s3 = sIdx[i + 6];
        float4 x0 = *(const float4*)(xb + (size_t)s0 * HIDK);
        float4 x1 = *(const float4*)(xb + (size_t)s1 * HIDK);
        float4 x2 = *(const float4*)(xb + (size_t)s2 * HIDK);
        float4 x3 = *(const float4*)(xb + (size_t)s3 * HIDK);
        a1[0] = fmaf(e0.x, x0.x, a1[0]); a1[1] = fmaf(e0.x, x0.y, a1[1]);
        a1[2] = fmaf(e0.x, x0.z, a1[2]); a1[3] = fmaf(e0.x, x0.w, a1[3]);
        a2[0] = fmaf(e0.y, x0.x, a2[0]); a2[1] = fmaf(e0.y, x0.y, a2[1]);
        a2[2] = fmaf(e0.y, x0.z, a2[2]); a2[3] = fmaf(e0.y, x0.w, a2[3]);
        z1 += e0.x; z2 += e0.y;
        a1[0] = fmaf(e1.x, x1.x, a1[0]); a1[1] = fmaf(e1.x, x1.y, a1[1]);
        a1[2] = fmaf(e1.x, x1.z, a1[2]); a1[3] = fmaf(e1.x, x1.w, a1[3]);
        a2[0] = fmaf(e1.y, x1.x, a2[0]); a2[1] = fmaf(e1.y, x1.y, a2[1]);
        a2[2] = fmaf(e1.y, x1.z, a2[2]); a2[3] = fmaf(e1.y, x1.w, a2[3]);
        z1 += e1.x; z2 += e1.y;
        a1[0] = fmaf(e2.x, x2.x, a1[0]); a1[1] = fmaf(e2.x, x2.y, a1[1]);
        a1[2] = fmaf(e2.x, x2.z, a1[2]); a1[3] = fmaf(e2.x, x2.w, a1[3]);
        a2[0] = fmaf(e2.y, x2.x, a2[0]); a2[1] = fmaf(e2.y, x2.y, a2[1]);
        a2[2] = fmaf(e2.y, x2.z, a2[2]); a2[3] = fmaf(e2.y, x2.w, a2[3]);
        z1 += e2.x; z2 += e2.y;
        a1[0] = fmaf(e3.x, x3.x, a1[0]); a1[1] = fmaf(e3.x, x3.y, a1[1]);
        a1[2] = fmaf(e3.x, x3.z, a1[2]); a1[3] = fmaf(e3.x, x3.w, a1[3]);
        a2[0] = fmaf(e3.y, x3.x, a2[0]); a2[1] = fmaf(e3.y, x3.y, a2[1]);
        a2[2] = fmaf(e3.y, x3.z, a2[2]); a2[3] = fmaf(e3.y, x3.w, a2[3]);
        z1 += e3.x; z2 += e3.y;
      }
      for (; i < i1; i += 2) {
        float2 e = sE[i];
        int s = sIdx[i];
        float4 xv = *(const float4*)(xb + (size_t)s * HIDK);
        a1[0] = fmaf(e.x, xv.x, a1[0]); a1[1] = fmaf(e.x, xv.y, a1[1]);
        a1[2] = fmaf(e.x, xv.z, a1[2]); a1[3] = fmaf(e.x, xv.w, a1[3]);
        a2[0] = fmaf(e.y, xv.x, a2[0]); a2[1] = fmaf(e.y, xv.y, a2[1]);
        a2[2] = fmaf(e.y, xv.z, a2[2]); a2[3] = fmaf(e.y, xv.w, a2[3]);
        z1 += e.x; z2 += e.y;
      }
      // combine the two slots; exclusive flush (no atomics, no zero-init)
      #pragma unroll
      for (int j = 0; j < 4; ++j) {
        a1[j] += __shfl_xor(a1[j], 32);
        a2[j] += __shfl_xor(a2[j], 32);
      }
      z1 += __shfl_xor(z1, 32);
      z2 += __shfl_xor(z2, 32);
      if (slot == 0) {
        #pragma unroll
        for (int j = 0; j < 4; ++j) {
          Bb[0][seg][cq * 4 + j] = a1[j];
          Bb[1][seg][cq * 4 + j] = a2[j];
        }
        if (cq == 0) { Bb[0][seg][128] = z1; Bb[1][seg][128] = z2; }
      }
    }
  }
  __syncthreads();

  // ---- stage W_h^T (aliases sE — dead after F) + scans ----
  float* WshT = (float*)sE;           // [128][16]
  const float* Wh = W + (size_t)h * 16 * 128;
  for (int v = tid; v < 2048; v += 512) {
    int k = v >> 4, cout = v & 15;
    WshT[k * 16 + cout] = Wh[(size_t)cout * 128 + k];
  }
  // scans over 51 buckets: which=0 -> exclusive suffix, which=1 -> inclusive prefix
  for (int task = tid; task < 258; task += 512) {
    int which = task >= 129;
    int c = task - which * 129;
    if (which == 0) {
      float run = 0.f;
      for (int k = 50; k >= 0; --k) { float tmp = Bb[0][k][c]; Bb[0][k][c] = run; run += tmp; }
    } else {
      float run = 0.f;
      for (int k = 0; k <= 50; ++k) { run += Bb[1][k][c]; Bb[1][k][c] = run; }
    }
  }
  __syncthreads();

  // ---- epilogue: project through W_h, divide, bias, store ego slice ----
  for (int task = tid; task < NT * NC; task += 512) {
    int t = task >> 4, cout = task & 15;
    int r = sRank[t];
    float F1 = sF1[t], F2 = sF2[t];
    float z = F1 * Bb[0][r][128] + F2 * Bb[1][r][128];
    const float* b1r = &Bb[0][r][0];
    const float* b2r = &Bb[1][r][0];
    float n1 = 0.f, n2 = 0.f;
    #pragma unroll 4
    for (int c = 0; c < 128; ++c) {
      float w = WshT[c * 16 + cout];
      n1 = fmaf(b1r[c], w, n1);
      n2 = fmaf(b2r[c], w, n2);
    }
    out[((size_t)b * SAT + t) * NOUT + h * 16 + cout] =
        (F1 * n1 + F2 * n2) / z + bias[h * 16 + cout];
  }
}

extern "C" void kernel_launch(void* const* d_in, const int* in_sizes, int n_in,
                              void* d_out, int out_size, void* d_ws, size_t ws_size,
                              hipStream_t stream) {
  const float* X       = (const float*)d_in[0];  // h (32,50,50,128)
  const float* Wm      = (const float*)d_in[1];  // W (512,128)
  const float* att_src = (const float*)d_in[2];  // (32,16)
  const float* att_dst = (const float*)d_in[3];  // (32,16)
  const float* bias    = (const float*)d_in[4];  // (512,)
  float* out = (float*)d_out;

  float* PQ = (float*)d_ws;
  float* u  = PQ + 64 * 128;
  float* dv = u + (size_t)NB * NH * SAT;

  hipLaunchKernelGGL(k_fill, dim3(40000), dim3(256), 0, stream, bias, out);
  hipLaunchKernelGGL(k0_pq, dim3(32), dim3(256), 0, stream, Wm, att_src, att_dst, PQ);
  hipLaunchKernelGGL(k1_ud, dim3(1250), dim3(256), 0, stream, X, PQ, u, dv);
  hipLaunchKernelGGL(k2_attn, dim3(1024), dim3(512), 0, stream,
                     X, u, dv, Wm, bias, out);
}

// Round 8
// 318.697 us; speedup vs baseline: 1.8162x; 1.0160x over previous
//
#include <hip/hip_runtime.h>
#include <math.h>

// Problem constants
#define NA    50
#define NT    50
#define HIDK  128
#define NH    32
#define NC    16
#define NB    32
#define SAT   2500    // NA*NT
#define NS    2450    // (NA-1)*NT
#define NOUT  512     // NH*NC

// ============ K_fill: out[b][a][t][:] = bias (ego slice overwritten by k2) ============
__global__ __launch_bounds__(256) void k_fill(const float* __restrict__ bias,
                                              float* __restrict__ out) {
  size_t i = (size_t)blockIdx.x * 256 + threadIdx.x;
  float4 b4 = ((const float4*)bias)[i & 127];
  ((float4*)out)[i] = b4;
}

// ============ K0: PQ[j][k] = sum_c att[j][c] * W[(j%32)*16+c][k] ============
__global__ __launch_bounds__(256) void k0_pq(const float* __restrict__ W,
                                             const float* __restrict__ att_src,
                                             const float* __restrict__ att_dst,
                                             float* __restrict__ PQ) {
  int g = blockIdx.x * 256 + threadIdx.x;   // 8192 total
  int j = g >> 7, k = g & 127;
  int hh = j & 31;
  const float* att = (j < 32) ? att_src : att_dst;
  float acc = 0.f;
  #pragma unroll
  for (int c = 0; c < 16; ++c)
    acc = fmaf(att[hh * 16 + c], W[(size_t)(hh * 16 + c) * 128 + k], acc);
  PQ[g] = acc;
}

// ============ K1: u[b][h][s] = x_row . p_h ; d[b][h][t] = x_ego_row . q_h ============
__global__ __launch_bounds__(256) void k1_ud(
    const float* __restrict__ X,     // (80000,128)
    const float* __restrict__ PQ,    // (64,128)
    float* __restrict__ u,           // [b][h][2500]
    float* __restrict__ dv)          // [b][h][50]
{
  __shared__ float Ast[32][68];
  __shared__ float Bst[32][68];
  const int tid = threadIdx.x;
  const int m0 = blockIdx.x * 64;
  const int ty = tid >> 4, tx = tid & 15;
  float acc[4][4] = {};
  const int sr = tid >> 3, sc = tid & 7;

  for (int kc = 0; kc < 128; kc += 32) {
    #pragma unroll
    for (int L = 0; L < 2; ++L) {
      int row = sr + L * 32;
      float4 v = *(const float4*)&X[(size_t)(m0 + row) * 128 + kc + sc * 4];
      Ast[sc*4+0][row] = v.x; Ast[sc*4+1][row] = v.y;
      Ast[sc*4+2][row] = v.z; Ast[sc*4+3][row] = v.w;
      float4 w = *(const float4*)&PQ[(size_t)row * 128 + kc + sc * 4];
      Bst[sc*4+0][row] = w.x; Bst[sc*4+1][row] = w.y;
      Bst[sc*4+2][row] = w.z; Bst[sc*4+3][row] = w.w;
    }
    __syncthreads();
    #pragma unroll
    for (int k = 0; k < 32; ++k) {
      float4 a4 = *(const float4*)&Ast[k][ty * 4];
      float4 b4 = *(const float4*)&Bst[k][tx * 4];
      float a[4] = {a4.x, a4.y, a4.z, a4.w};
      float bb[4] = {b4.x, b4.y, b4.z, b4.w};
      #pragma unroll
      for (int i = 0; i < 4; ++i)
        #pragma unroll
        for (int j = 0; j < 4; ++j)
          acc[i][j] = fmaf(a[i], bb[j], acc[i][j]);
    }
    __syncthreads();
  }

  #pragma unroll
  for (int i = 0; i < 4; ++i) {
    int m = m0 + ty * 4 + i;
    int b = m / SAT, s = m - b * SAT;
    #pragma unroll
    for (int jj = 0; jj < 4; ++jj) {
      int col = tx * 4 + jj;
      if (col < 32)
        u[(size_t)(b * 32 + col) * SAT + s] = acc[i][jj];
      else if (s < NT)
        dv[(size_t)(b * 32 + col - 32) * NT + s] = acc[i][jj];
    }
  }
}

// ============ K2: bucket-decomposed attention in x-space ============
// R5: serial indirect scalar loads. R6: branchy flush kills pipelining.
// R7: branch-free but un-pipelined + 52-VGPR budget -> each group exposes full
// ds_read->global_load latency (VALUBusy 35%). Fix: depth-2 software pipeline
// with parity register buffers (no copies -> partial vmcnt waits) and
// __launch_bounds__(512,4) for a 128-VGPR budget.
#define LOADG(B_, g_) do {                                                  \
    _Pragma("unroll")                                                       \
    for (int j = 0; j < 4; ++j) {                                           \
      int idx_ = base + 2 * ((g_) * 4 + j);                                 \
      e##B_[j] = sE[idx_]; s##B_[j] = sIdx[idx_];                           \
    }                                                                       \
    _Pragma("unroll")                                                       \
    for (int j = 0; j < 4; ++j)                                             \
      x##B_[j] = *(const float4*)(xb + (size_t)s##B_[j] * HIDK);            \
  } while (0)

#define COMPG(B_) do {                                                      \
    _Pragma("unroll")                                                       \
    for (int j = 0; j < 4; ++j) {                                           \
      float2 ee = e##B_[j]; float4 xx = x##B_[j];                           \
      a1[0]=fmaf(ee.x,xx.x,a1[0]); a1[1]=fmaf(ee.x,xx.y,a1[1]);             \
      a1[2]=fmaf(ee.x,xx.z,a1[2]); a1[3]=fmaf(ee.x,xx.w,a1[3]);             \
      a2[0]=fmaf(ee.y,xx.x,a2[0]); a2[1]=fmaf(ee.y,xx.y,a2[1]);             \
      a2[2]=fmaf(ee.y,xx.z,a2[2]); a2[3]=fmaf(ee.y,xx.w,a2[3]);             \
      z1 += ee.x; z2 += ee.y;                                               \
    }                                                                       \
  } while (0)

__global__ __launch_bounds__(512, 4) void k2_attn(
    const float* __restrict__ X,     // (32,2500,128)
    const float* __restrict__ u,     // [b][h][2500]
    const float* __restrict__ dv,    // [b][h][50]
    const float* __restrict__ W,     // (512,128)
    const float* __restrict__ bias,  // (512)
    float* __restrict__ out)
{
  const int id = blockIdx.x;
  const int b  = (id & 7) + 8 * (id >> 8);   // <=2 X-slices per XCD L2 window
  const int h  = (id >> 3) & 31;
  const int tid = threadIdx.x;

  __shared__ float Bb[2][51][129];   // [which][bucket][c]; c==128 = z   52.6 KB
  __shared__ float2 sE[NS];          // sorted (e1,e2)                   19.6 KB
  __shared__ unsigned short sIdx[NS];// sorted sat-index                  4.9 KB
  __shared__ float sTheta[50], sD[50], sF1[50], sF2[50];
  __shared__ int   sRank[50];
  __shared__ int   offs[52];
  __shared__ int   offCur[51];
  __shared__ float red[8];
  __shared__ float sMaxU;

  float* sU = &Bb[0][0][0];                       // alias (dead before F)
  unsigned short* sBeta = (unsigned short*)&Bb[1][0][0];  // alias (dead before F)

  const size_t bh = (size_t)b * 32 + h;
  const float* uP = u + bh * SAT + NT;   // skip ego rows
  for (int i = tid; i < NS; i += 512) sU[i] = uP[i];
  if (tid < 50) sD[tid] = dv[bh * NT + tid];
  if (tid < 51) offCur[tid] = 0;
  __syncthreads();

  // ---- maxU ----
  float mx = -1e30f;
  for (int i = tid; i < NS; i += 512) mx = fmaxf(mx, sU[i]);
  #pragma unroll
  for (int o = 32; o; o >>= 1) mx = fmaxf(mx, __shfl_xor(mx, o));
  if ((tid & 63) == 0) red[tid >> 6] = mx;
  __syncthreads();
  if (tid == 0) {
    float m2 = red[0];
    #pragma unroll
    for (int k = 1; k < 8; ++k) m2 = fmaxf(m2, red[k]);
    sMaxU = m2;
  }
  __syncthreads();
  const float maxU = sMaxU;

  // ---- theta rank-sort + per-query factors ----
  if (tid < 50) {
    float th = -sD[tid];
    int r = 0;
    for (int t2 = 0; t2 < 50; ++t2) {
      float th2 = -sD[t2];
      r += (th2 < th) || (th2 == th && t2 < tid);
    }
    sRank[tid] = r;
    sTheta[r] = th;
    float x = maxU + sD[tid];
    float L = (x >= 0.f) ? x : 0.2f * x;
    sF1[tid] = __expf(x - L);
    sF2[tid] = __expf(0.2f * x - L);
  }
  __syncthreads();

  // ---- histogram (store beta once; reuse in scatter) ----
  for (int i = tid; i < NS; i += 512) {
    float uu = sU[i];
    int lo = 0, hi = 50;
    while (lo < hi) { int mid = (lo + hi) >> 1; if (sTheta[mid] <= uu) lo = mid + 1; else hi = mid; }
    sBeta[i] = (unsigned short)lo;
    atomicAdd(&offCur[lo], 1);
  }
  __syncthreads();
  if (tid == 0) {
    int run = 0;
    for (int k = 0; k < 51; ++k) { int c = offCur[k]; offs[k] = run; run += c; }
    offs[51] = run;  // 2450
  }
  __syncthreads();
  if (tid < 51) offCur[tid] = offs[tid];
  __syncthreads();

  // ---- scatter: sorted (e1,e2,satIdx) ----
  for (int i = tid; i < NS; i += 512) {
    float uu = sU[i];
    int beta = sBeta[i];
    int pos = atomicAdd(&offCur[beta], 1);
    sE[pos] = make_float2(__expf(uu - maxU), __expf(0.2f * (uu - maxU)));
    sIdx[pos] = (unsigned short)(i + NT);
  }
  __syncthreads();

  // ---- F: wave-owned segments, depth-2 software-pipelined gather ----
  {
    const int wave = tid >> 6;        // 0..7
    const int lane = tid & 63;
    const int slot = lane >> 5;       // which source of the pair
    const int cq   = lane & 31;       // channel quad cq*4..+3
    const float* xb = X + (size_t)b * SAT * HIDK + cq * 4;

    for (int seg = wave; seg < 51; seg += 8) {
      const int i0 = offs[seg], i1 = offs[seg + 1];
      const int base = i0 + slot;
      int np = i1 - base;                 // pairs this slot owns
      np = (np > 0) ? ((np + 1) >> 1) : 0;
      const int G = np >> 2;              // full groups of 4 pairs

      float a1[4] = {0.f, 0.f, 0.f, 0.f};
      float a2[4] = {0.f, 0.f, 0.f, 0.f};
      float z1 = 0.f, z2 = 0.f;

      float2 eA[4], eB[4]; int sA[4], sB[4]; float4 xA[4], xB[4];
      int g = 0;
      if (G) LOADG(A, 0);
      while (g + 2 <= G) {
        LOADG(B, g + 1);                  // prefetch next while computing cur
        COMPG(A);
        if (g + 2 < G) LOADG(A, g + 2);
        COMPG(B);
        g += 2;
      }
      if (g < G) COMPG(A);
      for (int k = G * 4; k < np; ++k) {  // remainder pairs
        int idx = base + 2 * k;
        float2 ee = sE[idx];
        int ss = sIdx[idx];
        float4 xx = *(const float4*)(xb + (size_t)ss * HIDK);
        a1[0]=fmaf(ee.x,xx.x,a1[0]); a1[1]=fmaf(ee.x,xx.y,a1[1]);
        a1[2]=fmaf(ee.x,xx.z,a1[2]); a1[3]=fmaf(ee.x,xx.w,a1[3]);
        a2[0]=fmaf(ee.y,xx.x,a2[0]); a2[1]=fmaf(ee.y,xx.y,a2[1]);
        a2[2]=fmaf(ee.y,xx.z,a2[2]); a2[3]=fmaf(ee.y,xx.w,a2[3]);
        z1 += ee.x; z2 += ee.y;
      }

      // combine the two slots; exclusive flush (no atomics, no zero-init)
      #pragma unroll
      for (int j = 0; j < 4; ++j) {
        a1[j] += __shfl_xor(a1[j], 32);
        a2[j] += __shfl_xor(a2[j], 32);
      }
      z1 += __shfl_xor(z1, 32);
      z2 += __shfl_xor(z2, 32);
      if (slot == 0) {
        #pragma unroll
        for (int j = 0; j < 4; ++j) {
          Bb[0][seg][cq * 4 + j] = a1[j];
          Bb[1][seg][cq * 4 + j] = a2[j];
        }
        if (cq == 0) { Bb[0][seg][128] = z1; Bb[1][seg][128] = z2; }
      }
    }
  }
  __syncthreads();

  // ---- stage W_h^T (aliases sE — dead after F) + scans ----
  float* WshT = (float*)sE;           // [128][16]
  const float* Wh = W + (size_t)h * 16 * 128;
  for (int v = tid; v < 2048; v += 512) {
    int k = v >> 4, cout = v & 15;
    WshT[k * 16 + cout] = Wh[(size_t)cout * 128 + k];
  }
  // scans over 51 buckets: which=0 -> exclusive suffix, which=1 -> inclusive prefix
  for (int task = tid; task < 258; task += 512) {
    int which = task >= 129;
    int c = task - which * 129;
    if (which == 0) {
      float run = 0.f;
      for (int k = 50; k >= 0; --k) { float tmp = Bb[0][k][c]; Bb[0][k][c] = run; run += tmp; }
    } else {
      float run = 0.f;
      for (int k = 0; k <= 50; ++k) { run += Bb[1][k][c]; Bb[1][k][c] = run; }
    }
  }
  __syncthreads();

  // ---- epilogue: project through W_h, divide, bias, store ego slice ----
  for (int task = tid; task < NT * NC; task += 512) {
    int t = task >> 4, cout = task & 15;
    int r = sRank[t];
    float F1 = sF1[t], F2 = sF2[t];
    float z = F1 * Bb[0][r][128] + F2 * Bb[1][r][128];
    const float* b1r = &Bb[0][r][0];
    const float* b2r = &Bb[1][r][0];
    float n1 = 0.f, n2 = 0.f;
    #pragma unroll 4
    for (int c = 0; c < 128; ++c) {
      float w = WshT[c * 16 + cout];
      n1 = fmaf(b1r[c], w, n1);
      n2 = fmaf(b2r[c], w, n2);
    }
    out[((size_t)b * SAT + t) * NOUT + h * 16 + cout] =
        (F1 * n1 + F2 * n2) / z + bias[h * 16 + cout];
  }
}

extern "C" void kernel_launch(void* const* d_in, const int* in_sizes, int n_in,
                              void* d_out, int out_size, void* d_ws, size_t ws_size,
                              hipStream_t stream) {
  const float* X       = (const float*)d_in[0];  // h (32,50,50,128)
  const float* Wm      = (const float*)d_in[1];  // W (512,128)
  const float* att_src = (const float*)d_in[2];  // (32,16)
  const float* att_dst = (const float*)d_in[3];  // (32,16)
  const float* bias    = (const float*)d_in[4];  // (512,)
  float* out = (float*)d_out;

  float* PQ = (float*)d_ws;
  float* u  = PQ + 64 * 128;
  float* dv = u + (size_t)NB * NH * SAT;

  hipLaunchKernelGGL(k_fill, dim3(40000), dim3(256), 0, stream, bias, out);
  hipLaunchKernelGGL(k0_pq, dim3(32), dim3(256), 0, stream, Wm, att_src, att_dst, PQ);
  hipLaunchKernelGGL(k1_ud, dim3(1250), dim3(256), 0, stream, X, PQ, u, dv);
  hipLaunchKernelGGL(k2_attn, dim3(1024), dim3(512), 0, stream,
                     X, u, dv, Wm, bias, out);
}